// Round 1
// baseline (234.619 us; speedup 1.0000x reference)
//
#include <hip/hip_runtime.h>

typedef unsigned short UST;
typedef unsigned int u32;
typedef __attribute__((ext_vector_type(8))) short short8;
typedef __attribute__((ext_vector_type(4))) float f32x4;

#define HPAD 258
#define CIN 256
#define COUT 512
#define KTOT 2304  // 256*9

// workspace partition (bytes)
#define WB_BYTES (COUT * KTOT * 2)            // 2,359,296
#define XBT_OFF  WB_BYTES
#define XBT_BYTES (HPAD * HPAD * CIN * 2)     // 34,076,672
#define ABSM_OFF (XBT_OFF + XBT_BYTES)
#define ABSM_BYTES (HPAD * HPAD * 4)          // 266,256
#define INK_OFF  (ABSM_OFF + ABSM_BYTES)

__device__ __forceinline__ UST f2bf(float f) {
  union { float f; u32 u; } c; c.f = f;
  u32 u = c.u;
  u += 0x7FFFu + ((u >> 16) & 1u);  // round-to-nearest-even
  return (UST)(u >> 16);
}

__device__ __forceinline__ void gload_lds16(const void* g, void* l) {
  __builtin_amdgcn_global_load_lds(
      (const __attribute__((address_space(1))) u32*)g,
      (__attribute__((address_space(3))) u32*)l, 16, 0, 0);
}

// ---- kernel 1: alpha-fold + reorder weights to [co][khkw*256+ci] bf16 ----
__global__ __launch_bounds__(256) void k_prep_w(const float* __restrict__ w,
                                                UST* __restrict__ wb) {
  int co = blockIdx.x;
  int ci = threadIdx.x;  // 0..255
  const float* wr = w + co * KTOT + ci * 9;
  float v[9];
  float s = 0.f;
#pragma unroll
  for (int j = 0; j < 9; ++j) { v[j] = wr[j]; s += v[j]; }
  __shared__ float red[256];
  red[ci] = s;
  __syncthreads();
#pragma unroll
  for (int off = 128; off > 0; off >>= 1) {
    if (ci < off) red[ci] += red[ci + off];
    __syncthreads();
  }
  float alpha = red[0] * (1.0f / 2304.0f);
  UST* wo = wb + co * KTOT + ci;
#pragma unroll
  for (int j = 0; j < 9; ++j) wo[j * 256] = f2bf(v[j] * alpha);
}

// ---- kernel 2: binarize + NCHW->NHWC transpose + channel-mean |x| ----
// grid (258, 5): hp = padded row, wt = 64-wide wp tile
__global__ __launch_bounds__(256) void k_binz(const float* __restrict__ x,
                                              UST* __restrict__ xbt,
                                              float* __restrict__ absm) {
  int hp = blockIdx.x;
  int wt = blockIdx.y;
  int wpl = threadIdx.x & 63;
  int chunk = threadIdx.x >> 6;  // 64-ci chunk
  int wp = wt * 64 + wpl;
  bool valid = wp < HPAD;
  int hx = hp - 1, wx = wp - 1;
  bool inb = valid && ((unsigned)hx < 256u) && ((unsigned)wx < 256u);
  float asum = 0.f;
  u32 pk[32];
#pragma unroll
  for (int c2 = 0; c2 < 32; ++c2) {
    int ci = chunk * 64 + c2 * 2;
    float v0 = 1.0f, v1 = 1.0f;
    if (inb) {
      v0 = x[(unsigned)ci * 65536u + (unsigned)(hx * 256 + wx)];
      v1 = x[(unsigned)(ci + 1) * 65536u + (unsigned)(hx * 256 + wx)];
    }
    asum += fabsf(v0) + fabsf(v1);
    u32 s0 = (v0 >= 0.f) ? 0x3F80u : 0xBF80u;
    u32 s1 = (v1 >= 0.f) ? 0x3F80u : 0xBF80u;
    pk[c2] = s0 | (s1 << 16);
  }
  if (valid) {
    uint4* dst = (uint4*)(xbt + ((unsigned)(hp * HPAD + wp) * 256u + chunk * 64));
#pragma unroll
    for (int g = 0; g < 8; ++g)
      dst[g] = make_uint4(pk[g * 4], pk[g * 4 + 1], pk[g * 4 + 2], pk[g * 4 + 3]);
  }
  __shared__ float red[4][64];
  red[chunk][wpl] = asum;
  __syncthreads();
  if (chunk == 0 && valid) {
    float tot = red[0][wpl] + red[1][wpl] + red[2][wpl] + red[3][wpl];
    absm[hp * HPAD + wp] = tot * (1.0f / 256.0f);
  }
}

// ---- kernel 3: 3x3 box filter / 9 ----
__global__ __launch_bounds__(256) void k_inputk(const float* __restrict__ absm,
                                                float* __restrict__ inK) {
  int h = blockIdx.x, w = threadIdx.x;
  float s = 0.f;
#pragma unroll
  for (int dh = 0; dh < 3; ++dh)
#pragma unroll
    for (int dw = 0; dw < 3; ++dw) s += absm[(h + dh) * HPAD + (w + dw)];
  inK[h * 256 + w] = s * (1.0f / 9.0f);
}

// ---- kernel 4: implicit-GEMM conv, 128x128 tile, 4 waves, BK=64 ----
__global__ __launch_bounds__(256) void k_conv(const UST* __restrict__ wb,
                                              const UST* __restrict__ xbt,
                                              const float* __restrict__ inK,
                                              float* __restrict__ out) {
  __shared__ __align__(16) UST As[128 * 64];  // [co_local][k_local], 128B rows, XOR-swizzled
  __shared__ __align__(16) UST Bs[128 * 64];  // [pix_local][ci_local]
  int tid = threadIdx.x;
  int bid = blockIdx.x;
  int mt = bid & 3;        // co tile (4)
  int nt = bid >> 2;       // pixel tile (512)
  int h = nt >> 1;
  int w0 = (nt & 1) << 7;
  int co0 = mt << 7;

  // staging geometry: per-thread constant (row, swizzled col) for 4 insts
  int qrow[4], qcolb[4];
#pragma unroll
  for (int i = 0; i < 4; ++i) {
    u32 q = (u32)(i * 256 + tid) * 16u;
    u32 p = q ^ (((q >> 7) & 7u) << 4);  // logical byte (involution)
    qrow[i] = (int)(p >> 7);
    qcolb[i] = (int)(p & 127u);
  }
  const char* wb_b = (const char*)wb;
  const char* xbt_b = (const char*)xbt;
  int aoff[4], boff[4];
#pragma unroll
  for (int i = 0; i < 4; ++i) {
    aoff[i] = (co0 + qrow[i]) * (KTOT * 2) + qcolb[i];
    boff[i] = (w0 + qrow[i]) * (CIN * 2) + qcolb[i];
  }
  u32 ldsq[4];
#pragma unroll
  for (int i = 0; i < 4; ++i) ldsq[i] = (u32)(i * 4096 + (tid >> 6) * 1024);  // wave-uniform dest

  int lane = tid & 63;
  int wv = tid >> 6;
  int wm = wv >> 1, wn = wv & 1;

  // ds_read addresses (loop-invariant), swizzled
  u32 ra[2][4], rb[2][4];
#pragma unroll
  for (int ks = 0; ks < 2; ++ks)
#pragma unroll
    for (int m = 0; m < 4; ++m) {
      u32 rowa = (u32)(wm * 64 + m * 16 + (lane & 15));
      u32 pa = rowa * 128u + (u32)(ks * 32 + ((lane >> 4) << 3)) * 2u;
      ra[ks][m] = pa ^ ((rowa & 7u) << 4);
      u32 rowb = (u32)(wn * 64 + m * 16 + (lane & 15));
      u32 pb = rowb * 128u + (u32)(ks * 32 + ((lane >> 4) << 3)) * 2u;
      rb[ks][m] = pb ^ ((rowb & 7u) << 4);
    }

  f32x4 acc[4][4];
#pragma unroll
  for (int m = 0; m < 4; ++m)
#pragma unroll
    for (int n = 0; n < 4; ++n) acc[m][n] = (f32x4){0.f, 0.f, 0.f, 0.f};

  for (int t = 0; t < 36; ++t) {
    int khkw = t >> 2;
    int kh = (khkw * 11) >> 5;  // /3 for 0..8
    int kw = khkw - kh * 3;
    int c0b = (t & 3) << 7;  // ci-chunk byte offset
    int brow_base = ((h + kh) * HPAD + kw) * (CIN * 2) + c0b;
#pragma unroll
    for (int i = 0; i < 4; ++i) {
      gload_lds16(wb_b + aoff[i] + t * 128, (char*)As + ldsq[i]);
      gload_lds16(xbt_b + brow_base + boff[i], (char*)Bs + ldsq[i]);
    }
    __syncthreads();  // drains vmcnt(0): tiles ready
#pragma unroll
    for (int ks = 0; ks < 2; ++ks) {
      short8 af[4], bf[4];
#pragma unroll
      for (int m = 0; m < 4; ++m)
        af[m] = *(const short8*)((const char*)As + ra[ks][m]);
#pragma unroll
      for (int n = 0; n < 4; ++n)
        bf[n] = *(const short8*)((const char*)Bs + rb[ks][n]);
#pragma unroll
      for (int m = 0; m < 4; ++m)
#pragma unroll
        for (int n = 0; n < 4; ++n)
          acc[m][n] = __builtin_amdgcn_mfma_f32_16x16x32_bf16(af[m], bf[n], acc[m][n], 0, 0, 0);
    }
    __syncthreads();  // protect LDS overwrite
  }

  // epilogue: out[co][h][w] = acc * input_K[h][w]  (alpha already folded)
  int col = lane & 15;
  int rg = lane >> 4;
#pragma unroll
  for (int n = 0; n < 4; ++n) {
    int w = w0 + wn * 64 + n * 16 + col;
    float kv = inK[h * 256 + w];
#pragma unroll
    for (int m = 0; m < 4; ++m) {
      int co = co0 + wm * 64 + m * 16 + rg * 4;
      float* o = out + (unsigned)co * 65536u + (unsigned)(h * 256 + w);
#pragma unroll
      for (int r = 0; r < 4; ++r) o[(unsigned)r * 65536u] = acc[m][n][r] * kv;
    }
  }
}

extern "C" void kernel_launch(void* const* d_in, const int* in_sizes, int n_in,
                              void* d_out, int out_size, void* d_ws, size_t ws_size,
                              hipStream_t stream) {
  const float* x = (const float*)d_in[0];   // [1,256,256,256] f32
  const float* w = (const float*)d_in[1];   // [512,256,3,3] f32
  float* out = (float*)d_out;               // [1,512,256,256] f32
  char* ws = (char*)d_ws;
  UST* wb = (UST*)ws;
  UST* xbt = (UST*)(ws + XBT_OFF);
  float* absm = (float*)(ws + ABSM_OFF);
  float* inK = (float*)(ws + INK_OFF);

  k_prep_w<<<COUT, 256, 0, stream>>>(w, wb);
  k_binz<<<dim3(HPAD, 5), 256, 0, stream>>>(x, xbt, absm);
  k_inputk<<<256, 256, 0, stream>>>(absm, inK);
  k_conv<<<2048, 256, 0, stream>>>(wb, xbt, inK, out);
}

// Round 2
// 175.099 us; speedup vs baseline: 1.3399x; 1.3399x over previous
//
#include <hip/hip_runtime.h>

typedef unsigned short UST;
typedef unsigned int u32;
typedef __attribute__((ext_vector_type(8))) short short8;
typedef __attribute__((ext_vector_type(4))) float f32x4;

#define HPAD 258
#define CIN 256
#define COUT 512
#define KTOT 2304  // 256*9
#define NT 36      // K-tiles of 64

// workspace partition (bytes)
#define WB_BYTES (COUT * KTOT * 2)
#define XBT_OFF  WB_BYTES
#define XBT_BYTES (HPAD * HPAD * CIN * 2)
#define ABSM_OFF (XBT_OFF + XBT_BYTES)
#define ABSM_BYTES (HPAD * HPAD * 4)
#define INK_OFF  (ABSM_OFF + ABSM_BYTES)

__device__ __forceinline__ UST f2bf(float f) {
  union { float f; u32 u; } c; c.f = f;
  u32 u = c.u;
  u += 0x7FFFu + ((u >> 16) & 1u);
  return (UST)(u >> 16);
}

__device__ __forceinline__ void gload_lds16(const void* g, void* l) {
  __builtin_amdgcn_global_load_lds(
      (const __attribute__((address_space(1))) u32*)g,
      (__attribute__((address_space(3))) u32*)l, 16, 0, 0);
}

// ---- kernel 1: alpha-fold + reorder weights to [co][khkw*256+ci] bf16 ----
__global__ __launch_bounds__(256) void k_prep_w(const float* __restrict__ w,
                                                UST* __restrict__ wb) {
  int co = blockIdx.x;
  int ci = threadIdx.x;
  const float* wr = w + co * KTOT + ci * 9;
  float v[9];
  float s = 0.f;
#pragma unroll
  for (int j = 0; j < 9; ++j) { v[j] = wr[j]; s += v[j]; }
  __shared__ float red[256];
  red[ci] = s;
  __syncthreads();
#pragma unroll
  for (int off = 128; off > 0; off >>= 1) {
    if (ci < off) red[ci] += red[ci + off];
    __syncthreads();
  }
  float alpha = red[0] * (1.0f / 2304.0f);
  UST* wo = wb + co * KTOT + ci;
#pragma unroll
  for (int j = 0; j < 9; ++j) wo[j * 256] = f2bf(v[j] * alpha);
}

// ---- kernel 2: binarize + NCHW->NHWC transpose + channel-mean |x| ----
__global__ __launch_bounds__(256) void k_binz(const float* __restrict__ x,
                                              UST* __restrict__ xbt,
                                              float* __restrict__ absm) {
  int hp = blockIdx.x;
  int wt = blockIdx.y;
  int wpl = threadIdx.x & 63;
  int chunk = threadIdx.x >> 6;
  int wp = wt * 64 + wpl;
  bool valid = wp < HPAD;
  int hx = hp - 1, wx = wp - 1;
  bool inb = valid && ((unsigned)hx < 256u) && ((unsigned)wx < 256u);
  float asum = 0.f;
  u32 pk[32];
#pragma unroll
  for (int c2 = 0; c2 < 32; ++c2) {
    int ci = chunk * 64 + c2 * 2;
    float v0 = 1.0f, v1 = 1.0f;
    if (inb) {
      v0 = x[(unsigned)ci * 65536u + (unsigned)(hx * 256 + wx)];
      v1 = x[(unsigned)(ci + 1) * 65536u + (unsigned)(hx * 256 + wx)];
    }
    asum += fabsf(v0) + fabsf(v1);
    u32 s0 = (v0 >= 0.f) ? 0x3F80u : 0xBF80u;
    u32 s1 = (v1 >= 0.f) ? 0x3F80u : 0xBF80u;
    pk[c2] = s0 | (s1 << 16);
  }
  if (valid) {
    uint4* dst = (uint4*)(xbt + ((unsigned)(hp * HPAD + wp) * 256u + chunk * 64));
#pragma unroll
    for (int g = 0; g < 8; ++g)
      dst[g] = make_uint4(pk[g * 4], pk[g * 4 + 1], pk[g * 4 + 2], pk[g * 4 + 3]);
  }
  __shared__ float red[4][64];
  red[chunk][wpl] = asum;
  __syncthreads();
  if (chunk == 0 && valid) {
    float tot = red[0][wpl] + red[1][wpl] + red[2][wpl] + red[3][wpl];
    absm[hp * HPAD + wp] = tot * (1.0f / 256.0f);
  }
}

// ---- kernel 3: 3x3 box filter / 9 ----
__global__ __launch_bounds__(256) void k_inputk(const float* __restrict__ absm,
                                                float* __restrict__ inK) {
  int h = blockIdx.x, w = threadIdx.x;
  float s = 0.f;
#pragma unroll
  for (int dh = 0; dh < 3; ++dh)
#pragma unroll
    for (int dw = 0; dw < 3; ++dw) s += absm[(h + dh) * HPAD + (w + dw)];
  inK[h * 256 + w] = s * (1.0f / 9.0f);
}

// ---- kernel 4: 256x256-tile 8-phase implicit-GEMM conv ----
// LDS layout (128 KiB):
//   A planes: lds + b*32768 + P*16384      [b=buffer, P=K-half]
//   B planes: lds + 65536 + b*32768 + P*16384
// Each plane: 256 rows x 32 k bf16, superrow-XOR swizzled:
//   logical (row, q[16B slot 0..3]) -> sr=row>>1, s=((row&1)<<2)|q,
//   byte = sr*128 + (s^(sr&7))*16
#define MM(a, b, c) __builtin_amdgcn_mfma_f32_16x16x32_bf16(a, b, c, 0, 0, 0)

#define A_LDS(B, P) (lds + (B) * 32768 + (P) * 16384)
#define B_LDS(B, P) (lds + 65536 + (B) * 32768 + (P) * 16384)
#define RD_A(B, P, M) (*(const short8*)(A_LDS(B, P) + swzA[M]))
#define RD_B(B, P, N) (*(const short8*)(B_LDS(B, P) + swzB[N]))

#define STAGE_A(TT, P, B) do { \
    const char* s_ = wb_b + (TT) * 128 + (P) * 64; \
    char* d_ = A_LDS(B, P) + wv * 1024; \
    gload_lds16(s_ + aoff0, d_); \
    gload_lds16(s_ + aoff1, d_ + 8192); } while (0)

#define STAGE_B(TT, P, B) do { \
    int tt_ = (TT); int khkw_ = tt_ >> 2; int kh_ = (khkw_ * 11) >> 5; \
    int kw_ = khkw_ - kh_ * 3; \
    const char* s_ = xbt_b + ((h + kh_) * HPAD + kw_) * 512 + (tt_ & 3) * 128 + (P) * 64; \
    char* d_ = B_LDS(B, P) + wv * 1024; \
    gload_lds16(s_ + boff0, d_); \
    gload_lds16(s_ + boff1, d_ + 8192); } while (0)

#define MFMA16(MB) \
  acc[(MB)+0][0]=MM(aF0,bF0,acc[(MB)+0][0]); acc[(MB)+0][1]=MM(aF0,bF1,acc[(MB)+0][1]); \
  acc[(MB)+0][2]=MM(aF0,bF2,acc[(MB)+0][2]); acc[(MB)+0][3]=MM(aF0,bF3,acc[(MB)+0][3]); \
  acc[(MB)+1][0]=MM(aF1,bF0,acc[(MB)+1][0]); acc[(MB)+1][1]=MM(aF1,bF1,acc[(MB)+1][1]); \
  acc[(MB)+1][2]=MM(aF1,bF2,acc[(MB)+1][2]); acc[(MB)+1][3]=MM(aF1,bF3,acc[(MB)+1][3]); \
  acc[(MB)+2][0]=MM(aF2,bF0,acc[(MB)+2][0]); acc[(MB)+2][1]=MM(aF2,bF1,acc[(MB)+2][1]); \
  acc[(MB)+2][2]=MM(aF2,bF2,acc[(MB)+2][2]); acc[(MB)+2][3]=MM(aF2,bF3,acc[(MB)+2][3]); \
  acc[(MB)+3][0]=MM(aF3,bF0,acc[(MB)+3][0]); acc[(MB)+3][1]=MM(aF3,bF1,acc[(MB)+3][1]); \
  acc[(MB)+3][2]=MM(aF3,bF2,acc[(MB)+3][2]); acc[(MB)+3][3]=MM(aF3,bF3,acc[(MB)+3][3]);

#define PH_SYNC \
  __builtin_amdgcn_s_barrier(); \
  asm volatile("s_waitcnt lgkmcnt(0)" ::: "memory"); \
  __builtin_amdgcn_s_setprio(1);
#define PH_END \
  __builtin_amdgcn_s_setprio(0); \
  __builtin_amdgcn_s_barrier();

#define TILE(T, CUR) do { \
  int t1 = (T) + 1; if (t1 >= NT) t1 = NT - 1; \
  int t2 = (T) + 2; if (t2 >= NT) t2 = NT - 1; \
  short8 bF0, bF1, bF2, bF3; \
  { /* ph1: ks0, m0-3 */ \
    short8 aF0 = RD_A(CUR,0,0), aF1 = RD_A(CUR,0,1), aF2 = RD_A(CUR,0,2), aF3 = RD_A(CUR,0,3); \
    bF0 = RD_B(CUR,0,0); bF1 = RD_B(CUR,0,1); bF2 = RD_B(CUR,0,2); bF3 = RD_B(CUR,0,3); \
    STAGE_A(t1, 1, (CUR)^1); \
    PH_SYNC; MFMA16(0); PH_END; \
  } \
  { /* ph2: ks0, m4-7 */ \
    short8 aF0 = RD_A(CUR,0,4), aF1 = RD_A(CUR,0,5), aF2 = RD_A(CUR,0,6), aF3 = RD_A(CUR,0,7); \
    STAGE_B(t1, 1, (CUR)^1); \
    PH_SYNC; MFMA16(4); PH_END; \
  } \
  { /* ph3: ks1, m0-3 */ \
    short8 aF0 = RD_A(CUR,1,0), aF1 = RD_A(CUR,1,1), aF2 = RD_A(CUR,1,2), aF3 = RD_A(CUR,1,3); \
    bF0 = RD_B(CUR,1,0); bF1 = RD_B(CUR,1,1); bF2 = RD_B(CUR,1,2); bF3 = RD_B(CUR,1,3); \
    STAGE_A(t2, 0, (CUR)); \
    PH_SYNC; MFMA16(0); PH_END; \
  } \
  { /* ph4: ks1, m4-7 + boundary counted vmcnt */ \
    short8 aF0 = RD_A(CUR,1,4), aF1 = RD_A(CUR,1,5), aF2 = RD_A(CUR,1,6), aF3 = RD_A(CUR,1,7); \
    STAGE_B(t2, 0, (CUR)); \
    PH_SYNC; MFMA16(4); \
    __builtin_amdgcn_s_setprio(0); \
    asm volatile("s_waitcnt vmcnt(4)" ::: "memory"); \
    __builtin_amdgcn_s_barrier(); \
  } \
} while (0)

__global__ __launch_bounds__(512, 2) void k_conv8(const UST* __restrict__ wb,
                                                  const UST* __restrict__ xbt,
                                                  const float* __restrict__ inK,
                                                  float* __restrict__ out) {
  __shared__ __align__(16) char lds[131072];
  int tid = threadIdx.x;
  int lane = tid & 63;
  int wv = tid >> 6;
  int wm = wv >> 2, wn = wv & 3;
  int bid = blockIdx.x;
  int bs = (bid & 7) * 64 + (bid >> 3);  // XCD-bijective swizzle (512 % 8 == 0)
  int mt = bs & 1;
  int h = bs >> 1;
  int co0 = mt << 8;

  // staging per-thread offsets (inverse-swizzled global source, linear LDS dest)
  int aoff0, aoff1, boff0, boff1;
  {
    u32 ql0 = (u32)tid * 16u, ql1 = (u32)(512 + tid) * 16u;
    u32 sr0 = ql0 >> 7, s0 = ((ql0 >> 4) & 7u) ^ (sr0 & 7u);
    u32 row0 = (sr0 << 1) | (s0 >> 2), q0 = s0 & 3u;
    u32 sr1 = ql1 >> 7, s1 = ((ql1 >> 4) & 7u) ^ (sr1 & 7u);
    u32 row1 = (sr1 << 1) | (s1 >> 2), q1 = s1 & 3u;
    aoff0 = (co0 + (int)row0) * 4608 + (int)q0 * 16;
    aoff1 = (co0 + (int)row1) * 4608 + (int)q1 * 16;
    boff0 = (int)row0 * 512 + (int)q0 * 16;
    boff1 = (int)row1 * 512 + (int)q1 * 16;
  }
  // ds_read swizzled offsets within a plane
  int swzA[8], swzB[4];
#pragma unroll
  for (int m = 0; m < 8; ++m) {
    u32 row = (u32)(wm * 128 + m * 16 + (lane & 15));
    u32 q = (u32)(lane >> 4);
    u32 sr = row >> 1, s = ((row & 1u) << 2) | q;
    swzA[m] = (int)(sr * 128u + (s ^ (sr & 7u)) * 16u);
  }
#pragma unroll
  for (int n = 0; n < 4; ++n) {
    u32 row = (u32)(wn * 64 + n * 16 + (lane & 15));
    u32 q = (u32)(lane >> 4);
    u32 sr = row >> 1, s = ((row & 1u) << 2) | q;
    swzB[n] = (int)(sr * 128u + (s ^ (sr & 7u)) * 16u);
  }

  const char* wb_b = (const char*)wb;
  const char* xbt_b = (const char*)xbt;

  f32x4 acc[8][4];
#pragma unroll
  for (int m = 0; m < 8; ++m)
#pragma unroll
    for (int n = 0; n < 4; ++n) acc[m][n] = (f32x4){0.f, 0.f, 0.f, 0.f};

  // prologue: tile0 fully, tile1 ks0; leave tile1-ks0 (4 insts) in flight
  STAGE_A(0, 0, 0); STAGE_B(0, 0, 0); STAGE_A(0, 1, 0); STAGE_B(0, 1, 0);
  STAGE_A(1, 0, 1); STAGE_B(1, 0, 1);
  asm volatile("s_waitcnt vmcnt(4)" ::: "memory");
  __builtin_amdgcn_s_barrier();

  for (int tp = 0; tp < NT / 2; ++tp) {
    int t0 = tp * 2;
    TILE(t0, 0);
    TILE(t0 + 1, 1);
  }

  // epilogue: scale by input_K, write NCHW
  int col = lane & 15, rg = lane >> 4;
  int pixbase = h * 256;
#pragma unroll
  for (int n = 0; n < 4; ++n) {
    int w = wn * 64 + n * 16 + col;
    float kv = inK[pixbase + w];
#pragma unroll
    for (int m = 0; m < 8; ++m) {
      int co = co0 + wm * 128 + m * 16 + rg * 4;
      float* o = out + (u32)co * 65536u + (u32)(pixbase + w);
#pragma unroll
      for (int r = 0; r < 4; ++r) o[(u32)r * 65536u] = acc[m][n][r] * kv;
    }
  }
}

extern "C" void kernel_launch(void* const* d_in, const int* in_sizes, int n_in,
                              void* d_out, int out_size, void* d_ws, size_t ws_size,
                              hipStream_t stream) {
  const float* x = (const float*)d_in[0];
  const float* w = (const float*)d_in[1];
  float* out = (float*)d_out;
  char* ws = (char*)d_ws;
  UST* wb = (UST*)ws;
  UST* xbt = (UST*)(ws + XBT_OFF);
  float* absm = (float*)(ws + ABSM_OFF);
  float* inK = (float*)(ws + INK_OFF);

  k_prep_w<<<COUT, 256, 0, stream>>>(w, wb);
  k_binz<<<dim3(HPAD, 5), 256, 0, stream>>>(x, xbt, absm);
  k_inputk<<<256, 256, 0, stream>>>(absm, inK);
  k_conv8<<<512, 512, 0, stream>>>(wb, xbt, inK, out);
}

// Round 3
// 173.633 us; speedup vs baseline: 1.3512x; 1.0084x over previous
//
#include <hip/hip_runtime.h>

typedef unsigned short UST;
typedef unsigned int u32;
typedef __attribute__((ext_vector_type(8))) short short8;
typedef __attribute__((ext_vector_type(4))) float f32x4;

#define HPAD 258
#define CIN 256
#define COUT 512
#define KTOT 2304  // 256*9
#define NT 36      // K-tiles of 64

// workspace partition (bytes)
#define WB_BYTES (COUT * KTOT * 2)
#define XBT_OFF  WB_BYTES
#define XBT_BYTES (HPAD * HPAD * CIN * 2)
#define ABSM_OFF (XBT_OFF + XBT_BYTES)
#define ABSM_BYTES (HPAD * HPAD * 4)
#define INK_OFF  (ABSM_OFF + ABSM_BYTES)

__device__ __forceinline__ UST f2bf(float f) {
  union { float f; u32 u; } c; c.f = f;
  u32 u = c.u;
  u += 0x7FFFu + ((u >> 16) & 1u);
  return (UST)(u >> 16);
}

__device__ __forceinline__ void gload_lds16(const void* g, void* l) {
  __builtin_amdgcn_global_load_lds(
      (const __attribute__((address_space(1))) u32*)g,
      (__attribute__((address_space(3))) u32*)l, 16, 0, 0);
}

// ---- kernel 1: alpha-fold + reorder weights to [co][khkw*256+ci] bf16 ----
__global__ __launch_bounds__(256) void k_prep_w(const float* __restrict__ w,
                                                UST* __restrict__ wb) {
  int co = blockIdx.x;
  int ci = threadIdx.x;
  const float* wr = w + co * KTOT + ci * 9;
  float v[9];
  float s = 0.f;
#pragma unroll
  for (int j = 0; j < 9; ++j) { v[j] = wr[j]; s += v[j]; }
  __shared__ float red[256];
  red[ci] = s;
  __syncthreads();
#pragma unroll
  for (int off = 128; off > 0; off >>= 1) {
    if (ci < off) red[ci] += red[ci + off];
    __syncthreads();
  }
  float alpha = red[0] * (1.0f / 2304.0f);
  UST* wo = wb + co * KTOT + ci;
#pragma unroll
  for (int j = 0; j < 9; ++j) wo[j * 256] = f2bf(v[j] * alpha);
}

// ---- kernel 2: binarize + NCHW->NHWC transpose + channel-mean |x| ----
__global__ __launch_bounds__(256) void k_binz(const float* __restrict__ x,
                                              UST* __restrict__ xbt,
                                              float* __restrict__ absm) {
  int hp = blockIdx.x;
  int wt = blockIdx.y;
  int wpl = threadIdx.x & 63;
  int chunk = threadIdx.x >> 6;
  int wp = wt * 64 + wpl;
  bool valid = wp < HPAD;
  int hx = hp - 1, wx = wp - 1;
  bool inb = valid && ((unsigned)hx < 256u) && ((unsigned)wx < 256u);
  float asum = 0.f;
  u32 pk[32];
#pragma unroll
  for (int c2 = 0; c2 < 32; ++c2) {
    int ci = chunk * 64 + c2 * 2;
    float v0 = 1.0f, v1 = 1.0f;
    if (inb) {
      v0 = x[(unsigned)ci * 65536u + (unsigned)(hx * 256 + wx)];
      v1 = x[(unsigned)(ci + 1) * 65536u + (unsigned)(hx * 256 + wx)];
    }
    asum += fabsf(v0) + fabsf(v1);
    u32 s0 = (v0 >= 0.f) ? 0x3F80u : 0xBF80u;
    u32 s1 = (v1 >= 0.f) ? 0x3F80u : 0xBF80u;
    pk[c2] = s0 | (s1 << 16);
  }
  if (valid) {
    uint4* dst = (uint4*)(xbt + ((unsigned)(hp * HPAD + wp) * 256u + chunk * 64));
#pragma unroll
    for (int g = 0; g < 8; ++g)
      dst[g] = make_uint4(pk[g * 4], pk[g * 4 + 1], pk[g * 4 + 2], pk[g * 4 + 3]);
  }
  __shared__ float red[4][64];
  red[chunk][wpl] = asum;
  __syncthreads();
  if (chunk == 0 && valid) {
    float tot = red[0][wpl] + red[1][wpl] + red[2][wpl] + red[3][wpl];
    absm[hp * HPAD + wp] = tot * (1.0f / 256.0f);
  }
}

// ---- kernel 3: 3x3 box filter / 9 ----
__global__ __launch_bounds__(256) void k_inputk(const float* __restrict__ absm,
                                                float* __restrict__ inK) {
  int h = blockIdx.x, w = threadIdx.x;
  float s = 0.f;
#pragma unroll
  for (int dh = 0; dh < 3; ++dh)
#pragma unroll
    for (int dw = 0; dw < 3; ++dw) s += absm[(h + dh) * HPAD + (w + dw)];
  inK[h * 256 + w] = s * (1.0f / 9.0f);
}

// ---- kernel 4: 256x256-tile free-running implicit-GEMM conv ----
// LDS layout (128 KiB):
//   A planes: lds + b*32768 + P*16384      [b=buffer, P=K-half]
//   B planes: lds + 65536 + b*32768 + P*16384
// Each plane: 256 rows x 32 k bf16, superrow-XOR swizzled:
//   logical (row, q[16B slot 0..3]) -> sr=row>>1, s=((row&1)<<2)|q,
//   byte = sr*128 + (s^(sr&7))*16
// Schedule: ONE barrier per K-tile; stage t+1 at tile start (full-tile slack
// so vmcnt(0) at tile end is stall-free); waves free-run reads+MFMA inside
// the tile so the LDS port overlaps the MFMA pipe instead of serializing.
#define MM(a, b, c) __builtin_amdgcn_mfma_f32_16x16x32_bf16(a, b, c, 0, 0, 0)

#define A_LDS(B, P) (lds + (B) * 32768 + (P) * 16384)
#define B_LDS(B, P) (lds + 65536 + (B) * 32768 + (P) * 16384)
#define RD_A(B, P, M) (*(const short8*)(A_LDS(B, P) + swzA[M]))
#define RD_B(B, P, N) (*(const short8*)(B_LDS(B, P) + swzB[N]))

#define STAGE_A(TT, P, B) do { \
    const char* s_ = wb_b + (TT) * 128 + (P) * 64; \
    char* d_ = A_LDS(B, P) + wv * 1024; \
    gload_lds16(s_ + aoff0, d_); \
    gload_lds16(s_ + aoff1, d_ + 8192); } while (0)

#define STAGE_B(TT, P, B) do { \
    int tt_ = (TT); int khkw_ = tt_ >> 2; int kh_ = (khkw_ * 11) >> 5; \
    int kw_ = khkw_ - kh_ * 3; \
    const char* s_ = xbt_b + ((h + kh_) * HPAD + kw_) * 512 + (tt_ & 3) * 128 + (P) * 64; \
    char* d_ = B_LDS(B, P) + wv * 1024; \
    gload_lds16(s_ + boff0, d_); \
    gload_lds16(s_ + boff1, d_ + 8192); } while (0)

// one K-tile, compile-time buffer index CUR
#define TILE_BODY(T, CUR) do { \
  if ((T) + 1 < NT) { \
    STAGE_A((T) + 1, 0, (CUR) ^ 1); STAGE_A((T) + 1, 1, (CUR) ^ 1); \
    STAGE_B((T) + 1, 0, (CUR) ^ 1); STAGE_B((T) + 1, 1, (CUR) ^ 1); \
  } \
  __builtin_amdgcn_sched_barrier(0); /* pin stage issue before compute */ \
  _Pragma("unroll") \
  for (int ks = 0; ks < 2; ++ks) { \
    short8 aF[8], bF[4]; \
    _Pragma("unroll") \
    for (int n = 0; n < 4; ++n) bF[n] = RD_B(CUR, ks, n); \
    _Pragma("unroll") \
    for (int m = 0; m < 8; ++m) aF[m] = RD_A(CUR, ks, m); \
    __builtin_amdgcn_s_setprio(1); \
    _Pragma("unroll") \
    for (int m = 0; m < 8; ++m) \
      _Pragma("unroll") \
      for (int n = 0; n < 4; ++n) \
        acc[m][n] = MM(aF[m], bF[n], acc[m][n]); \
    __builtin_amdgcn_s_setprio(0); \
  } \
  asm volatile("s_waitcnt vmcnt(0)" ::: "memory"); \
  __builtin_amdgcn_s_barrier(); \
} while (0)

__global__ __launch_bounds__(512, 2) void k_conv8(const UST* __restrict__ wb,
                                                  const UST* __restrict__ xbt,
                                                  const float* __restrict__ inK,
                                                  float* __restrict__ out) {
  __shared__ __align__(16) char lds[131072];
  int tid = threadIdx.x;
  int lane = tid & 63;
  int wv = tid >> 6;
  int wm = wv >> 2, wn = wv & 3;
  int bid = blockIdx.x;
  int bs = (bid & 7) * 64 + (bid >> 3);  // XCD-bijective swizzle (512 % 8 == 0)
  int mt = bs & 1;
  int h = bs >> 1;
  int co0 = mt << 8;

  // staging per-thread offsets (inverse-swizzled global source, linear LDS dest)
  int aoff0, aoff1, boff0, boff1;
  {
    u32 ql0 = (u32)tid * 16u, ql1 = (u32)(512 + tid) * 16u;
    u32 sr0 = ql0 >> 7, s0 = ((ql0 >> 4) & 7u) ^ (sr0 & 7u);
    u32 row0 = (sr0 << 1) | (s0 >> 2), q0 = s0 & 3u;
    u32 sr1 = ql1 >> 7, s1 = ((ql1 >> 4) & 7u) ^ (sr1 & 7u);
    u32 row1 = (sr1 << 1) | (s1 >> 2), q1 = s1 & 3u;
    aoff0 = (co0 + (int)row0) * 4608 + (int)q0 * 16;
    aoff1 = (co0 + (int)row1) * 4608 + (int)q1 * 16;
    boff0 = (int)row0 * 512 + (int)q0 * 16;
    boff1 = (int)row1 * 512 + (int)q1 * 16;
  }
  // ds_read swizzled offsets within a plane
  int swzA[8], swzB[4];
#pragma unroll
  for (int m = 0; m < 8; ++m) {
    u32 row = (u32)(wm * 128 + m * 16 + (lane & 15));
    u32 q = (u32)(lane >> 4);
    u32 sr = row >> 1, s = ((row & 1u) << 2) | q;
    swzA[m] = (int)(sr * 128u + (s ^ (sr & 7u)) * 16u);
  }
#pragma unroll
  for (int n = 0; n < 4; ++n) {
    u32 row = (u32)(wn * 64 + n * 16 + (lane & 15));
    u32 q = (u32)(lane >> 4);
    u32 sr = row >> 1, s = ((row & 1u) << 2) | q;
    swzB[n] = (int)(sr * 128u + (s ^ (sr & 7u)) * 16u);
  }

  const char* wb_b = (const char*)wb;
  const char* xbt_b = (const char*)xbt;

  f32x4 acc[8][4];
#pragma unroll
  for (int m = 0; m < 8; ++m)
#pragma unroll
    for (int n = 0; n < 4; ++n) acc[m][n] = (f32x4){0.f, 0.f, 0.f, 0.f};

  // prologue: stage tile 0 fully into buf 0
  STAGE_A(0, 0, 0); STAGE_A(0, 1, 0);
  STAGE_B(0, 0, 0); STAGE_B(0, 1, 0);
  asm volatile("s_waitcnt vmcnt(0)" ::: "memory");
  __builtin_amdgcn_s_barrier();

  for (int tp = 0; tp < NT / 2; ++tp) {
    int t0 = tp * 2;
    TILE_BODY(t0, 0);
    TILE_BODY(t0 + 1, 1);
  }

  // epilogue: scale by input_K, write NCHW
  int col = lane & 15, rg = lane >> 4;
  int pixbase = h * 256;
#pragma unroll
  for (int n = 0; n < 4; ++n) {
    int w = wn * 64 + n * 16 + col;
    float kv = inK[pixbase + w];
#pragma unroll
    for (int m = 0; m < 8; ++m) {
      int co = co0 + wm * 128 + m * 16 + rg * 4;
      float* o = out + (u32)co * 65536u + (u32)(pixbase + w);
#pragma unroll
      for (int r = 0; r < 4; ++r) o[(u32)r * 65536u] = acc[m][n][r] * kv;
    }
  }
}

extern "C" void kernel_launch(void* const* d_in, const int* in_sizes, int n_in,
                              void* d_out, int out_size, void* d_ws, size_t ws_size,
                              hipStream_t stream) {
  const float* x = (const float*)d_in[0];
  const float* w = (const float*)d_in[1];
  float* out = (float*)d_out;
  char* ws = (char*)d_ws;
  UST* wb = (UST*)ws;
  UST* xbt = (UST*)(ws + XBT_OFF);
  float* absm = (float*)(ws + ABSM_OFF);
  float* inK = (float*)(ws + INK_OFF);

  k_prep_w<<<COUT, 256, 0, stream>>>(w, wb);
  k_binz<<<dim3(HPAD, 5), 256, 0, stream>>>(x, xbt, absm);
  k_inputk<<<256, 256, 0, stream>>>(absm, inK);
  k_conv8<<<512, 512, 0, stream>>>(wb, xbt, inK, out);
}

// Round 4
// 168.260 us; speedup vs baseline: 1.3944x; 1.0319x over previous
//
#include <hip/hip_runtime.h>

typedef unsigned short UST;
typedef unsigned int u32;
typedef __attribute__((ext_vector_type(8))) short short8;
typedef __attribute__((ext_vector_type(4))) float f32x4;

#define HPAD 258
#define CIN 256
#define COUT 512
#define KTOT 2304  // 256*9
#define NT 36      // K-tiles of 64

// workspace partition (bytes)
#define WB_BYTES (COUT * KTOT * 2)
#define XBT_OFF  WB_BYTES
#define XBT_BYTES (HPAD * HPAD * CIN * 2)
#define ABSM_OFF (XBT_OFF + XBT_BYTES)
#define ABSM_BYTES (HPAD * HPAD * 4)
#define INK_OFF  (ABSM_OFF + ABSM_BYTES)

__device__ __forceinline__ UST f2bf(float f) {
  union { float f; u32 u; } c; c.f = f;
  u32 u = c.u;
  u += 0x7FFFu + ((u >> 16) & 1u);
  return (UST)(u >> 16);
}

__device__ __forceinline__ void gload_lds16(const void* g, void* l) {
  __builtin_amdgcn_global_load_lds(
      (const __attribute__((address_space(1))) u32*)g,
      (__attribute__((address_space(3))) u32*)l, 16, 0, 0);
}

// ---- kernel 1: alpha-fold + reorder weights to [co][khkw*256+ci] bf16 ----
__global__ __launch_bounds__(256) void k_prep_w(const float* __restrict__ w,
                                                UST* __restrict__ wb) {
  int co = blockIdx.x;
  int ci = threadIdx.x;
  const float* wr = w + co * KTOT + ci * 9;
  float v[9];
  float s = 0.f;
#pragma unroll
  for (int j = 0; j < 9; ++j) { v[j] = wr[j]; s += v[j]; }
  __shared__ float red[256];
  red[ci] = s;
  __syncthreads();
#pragma unroll
  for (int off = 128; off > 0; off >>= 1) {
    if (ci < off) red[ci] += red[ci + off];
    __syncthreads();
  }
  float alpha = red[0] * (1.0f / 2304.0f);
  UST* wo = wb + co * KTOT + ci;
#pragma unroll
  for (int j = 0; j < 9; ++j) wo[j * 256] = f2bf(v[j] * alpha);
}

// ---- kernel 2: binarize + NCHW->NHWC transpose + channel-mean |x| ----
__global__ __launch_bounds__(256) void k_binz(const float* __restrict__ x,
                                              UST* __restrict__ xbt,
                                              float* __restrict__ absm) {
  int hp = blockIdx.x;
  int wt = blockIdx.y;
  int wpl = threadIdx.x & 63;
  int chunk = threadIdx.x >> 6;
  int wp = wt * 64 + wpl;
  bool valid = wp < HPAD;
  int hx = hp - 1, wx = wp - 1;
  bool inb = valid && ((unsigned)hx < 256u) && ((unsigned)wx < 256u);
  float asum = 0.f;
  u32 pk[32];
#pragma unroll
  for (int c2 = 0; c2 < 32; ++c2) {
    int ci = chunk * 64 + c2 * 2;
    float v0 = 1.0f, v1 = 1.0f;
    if (inb) {
      v0 = x[(unsigned)ci * 65536u + (unsigned)(hx * 256 + wx)];
      v1 = x[(unsigned)(ci + 1) * 65536u + (unsigned)(hx * 256 + wx)];
    }
    asum += fabsf(v0) + fabsf(v1);
    u32 s0 = (v0 >= 0.f) ? 0x3F80u : 0xBF80u;
    u32 s1 = (v1 >= 0.f) ? 0x3F80u : 0xBF80u;
    pk[c2] = s0 | (s1 << 16);
  }
  if (valid) {
    uint4* dst = (uint4*)(xbt + ((unsigned)(hp * HPAD + wp) * 256u + chunk * 64));
#pragma unroll
    for (int g = 0; g < 8; ++g)
      dst[g] = make_uint4(pk[g * 4], pk[g * 4 + 1], pk[g * 4 + 2], pk[g * 4 + 3]);
  }
  __shared__ float red[4][64];
  red[chunk][wpl] = asum;
  __syncthreads();
  if (chunk == 0 && valid) {
    float tot = red[0][wpl] + red[1][wpl] + red[2][wpl] + red[3][wpl];
    absm[hp * HPAD + wp] = tot * (1.0f / 256.0f);
  }
}

// ---- kernel 3: 3x3 box filter / 9 ----
__global__ __launch_bounds__(256) void k_inputk(const float* __restrict__ absm,
                                                float* __restrict__ inK) {
  int h = blockIdx.x, w = threadIdx.x;
  float s = 0.f;
#pragma unroll
  for (int dh = 0; dh < 3; ++dh)
#pragma unroll
    for (int dw = 0; dw < 3; ++dw) s += absm[(h + dh) * HPAD + (w + dw)];
  inK[h * 256 + w] = s * (1.0f / 9.0f);
}

// ---- kernel 4: 256x256-tile implicit-GEMM conv, read-hoisted tile body ----
// LDS layout (128 KiB):
//   A planes: lds + b*32768 + P*16384      [b=buffer, P=K-half]
//   B planes: lds + 65536 + b*32768 + P*16384
// Each plane: 256 rows x 32 k bf16, superrow-XOR swizzled:
//   logical (row, q[16B slot 0..3]) -> sr=row>>1, s=((row&1)<<2)|q,
//   byte = sr*128 + (s^(sr&7))*16
// Per tile: ALL 24 ds_reads issue first (no setprio fence between them and
// the MFMA cluster), then the 8 stage DMAs for t+1, then one 64-MFMA
// cluster. The compiler's counted lgkmcnt lets MFMAs start as operands
// land, so the LDS port drains UNDER the MFMA stream instead of before it.
#define MM(a, b, c) __builtin_amdgcn_mfma_f32_16x16x32_bf16(a, b, c, 0, 0, 0)

#define A_LDS(B, P) (lds + (B) * 32768 + (P) * 16384)
#define B_LDS(B, P) (lds + 65536 + (B) * 32768 + (P) * 16384)
#define RD_A(B, P, M) (*(const short8*)(A_LDS(B, P) + swzA[M]))
#define RD_B(B, P, N) (*(const short8*)(B_LDS(B, P) + swzB[N]))

#define STAGE_A(TT, P, B) do { \
    const char* s_ = wb_b + (TT) * 128 + (P) * 64; \
    char* d_ = A_LDS(B, P) + wv * 1024; \
    gload_lds16(s_ + aoff0, d_); \
    gload_lds16(s_ + aoff1, d_ + 8192); } while (0)

#define STAGE_B(TT, P, B) do { \
    int tt_ = (TT); int khkw_ = tt_ >> 2; int kh_ = (khkw_ * 11) >> 5; \
    int kw_ = khkw_ - kh_ * 3; \
    const char* s_ = xbt_b + ((h + kh_) * HPAD + kw_) * 512 + (tt_ & 3) * 128 + (P) * 64; \
    char* d_ = B_LDS(B, P) + wv * 1024; \
    gload_lds16(s_ + boff0, d_); \
    gload_lds16(s_ + boff1, d_ + 8192); } while (0)

// one K-tile, compile-time buffer index CUR
#define TILE_BODY(T, CUR) do { \
  short8 b0[4], a0[8], b1[4], a1[8]; \
  _Pragma("unroll") for (int n = 0; n < 4; ++n) b0[n] = RD_B(CUR, 0, n); \
  _Pragma("unroll") for (int m = 0; m < 8; ++m) a0[m] = RD_A(CUR, 0, m); \
  _Pragma("unroll") for (int n = 0; n < 4; ++n) b1[n] = RD_B(CUR, 1, n); \
  _Pragma("unroll") for (int m = 0; m < 8; ++m) a1[m] = RD_A(CUR, 1, m); \
  if ((T) + 1 < NT) { \
    STAGE_A((T) + 1, 0, (CUR) ^ 1); STAGE_A((T) + 1, 1, (CUR) ^ 1); \
    STAGE_B((T) + 1, 0, (CUR) ^ 1); STAGE_B((T) + 1, 1, (CUR) ^ 1); \
  } \
  __builtin_amdgcn_s_setprio(1); \
  _Pragma("unroll") \
  for (int m = 0; m < 8; ++m) \
    _Pragma("unroll") \
    for (int n = 0; n < 4; ++n) \
      acc[m][n] = MM(a0[m], b0[n], acc[m][n]); \
  _Pragma("unroll") \
  for (int m = 0; m < 8; ++m) \
    _Pragma("unroll") \
    for (int n = 0; n < 4; ++n) \
      acc[m][n] = MM(a1[m], b1[n], acc[m][n]); \
  __builtin_amdgcn_s_setprio(0); \
  asm volatile("s_waitcnt vmcnt(0)" ::: "memory"); \
  __builtin_amdgcn_s_barrier(); \
} while (0)

__global__ __launch_bounds__(512, 2) void k_conv8(const UST* __restrict__ wb,
                                                  const UST* __restrict__ xbt,
                                                  const float* __restrict__ inK,
                                                  float* __restrict__ out) {
  __shared__ __align__(16) char lds[131072];
  int tid = threadIdx.x;
  int lane = tid & 63;
  int wv = tid >> 6;
  int wm = wv >> 2, wn = wv & 3;
  int bid = blockIdx.x;
  int bs = (bid & 7) * 64 + (bid >> 3);  // XCD-bijective swizzle (512 % 8 == 0)
  int mt = bs & 1;
  int h = bs >> 1;
  int co0 = mt << 8;

  // staging per-thread offsets (inverse-swizzled global source, linear LDS dest)
  int aoff0, aoff1, boff0, boff1;
  {
    u32 ql0 = (u32)tid * 16u, ql1 = (u32)(512 + tid) * 16u;
    u32 sr0 = ql0 >> 7, s0 = ((ql0 >> 4) & 7u) ^ (sr0 & 7u);
    u32 row0 = (sr0 << 1) | (s0 >> 2), q0 = s0 & 3u;
    u32 sr1 = ql1 >> 7, s1 = ((ql1 >> 4) & 7u) ^ (sr1 & 7u);
    u32 row1 = (sr1 << 1) | (s1 >> 2), q1 = s1 & 3u;
    aoff0 = (co0 + (int)row0) * 4608 + (int)q0 * 16;
    aoff1 = (co0 + (int)row1) * 4608 + (int)q1 * 16;
    boff0 = (int)row0 * 512 + (int)q0 * 16;
    boff1 = (int)row1 * 512 + (int)q1 * 16;
  }
  // ds_read swizzled offsets within a plane
  int swzA[8], swzB[4];
#pragma unroll
  for (int m = 0; m < 8; ++m) {
    u32 row = (u32)(wm * 128 + m * 16 + (lane & 15));
    u32 q = (u32)(lane >> 4);
    u32 sr = row >> 1, s = ((row & 1u) << 2) | q;
    swzA[m] = (int)(sr * 128u + (s ^ (sr & 7u)) * 16u);
  }
#pragma unroll
  for (int n = 0; n < 4; ++n) {
    u32 row = (u32)(wn * 64 + n * 16 + (lane & 15));
    u32 q = (u32)(lane >> 4);
    u32 sr = row >> 1, s = ((row & 1u) << 2) | q;
    swzB[n] = (int)(sr * 128u + (s ^ (sr & 7u)) * 16u);
  }

  const char* wb_b = (const char*)wb;
  const char* xbt_b = (const char*)xbt;

  f32x4 acc[8][4];
#pragma unroll
  for (int m = 0; m < 8; ++m)
#pragma unroll
    for (int n = 0; n < 4; ++n) acc[m][n] = (f32x4){0.f, 0.f, 0.f, 0.f};

  // prologue: stage tile 0 fully into buf 0
  STAGE_A(0, 0, 0); STAGE_A(0, 1, 0);
  STAGE_B(0, 0, 0); STAGE_B(0, 1, 0);
  asm volatile("s_waitcnt vmcnt(0)" ::: "memory");
  __builtin_amdgcn_s_barrier();

  for (int tp = 0; tp < NT / 2; ++tp) {
    int t0 = tp * 2;
    TILE_BODY(t0, 0);
    TILE_BODY(t0 + 1, 1);
  }

  // epilogue: scale by input_K, write NCHW
  int col = lane & 15, rg = lane >> 4;
  int pixbase = h * 256;
#pragma unroll
  for (int n = 0; n < 4; ++n) {
    int w = wn * 64 + n * 16 + col;
    float kv = inK[pixbase + w];
#pragma unroll
    for (int m = 0; m < 8; ++m) {
      int co = co0 + wm * 128 + m * 16 + rg * 4;
      float* o = out + (u32)co * 65536u + (u32)(pixbase + w);
#pragma unroll
      for (int r = 0; r < 4; ++r) o[(u32)r * 65536u] = acc[m][n][r] * kv;
    }
  }
}

extern "C" void kernel_launch(void* const* d_in, const int* in_sizes, int n_in,
                              void* d_out, int out_size, void* d_ws, size_t ws_size,
                              hipStream_t stream) {
  const float* x = (const float*)d_in[0];
  const float* w = (const float*)d_in[1];
  float* out = (float*)d_out;
  char* ws = (char*)d_ws;
  UST* wb = (UST*)ws;
  UST* xbt = (UST*)(ws + XBT_OFF);
  float* absm = (float*)(ws + ABSM_OFF);
  float* inK = (float*)(ws + INK_OFF);

  k_prep_w<<<COUT, 256, 0, stream>>>(w, wb);
  k_binz<<<dim3(HPAD, 5), 256, 0, stream>>>(x, xbt, absm);
  k_inputk<<<256, 256, 0, stream>>>(absm, inK);
  k_conv8<<<512, 512, 0, stream>>>(wb, xbt, inK, out);
}

// Round 5
// 163.660 us; speedup vs baseline: 1.4336x; 1.0281x over previous
//
#include <hip/hip_runtime.h>

typedef unsigned short UST;
typedef unsigned int u32;
typedef __attribute__((ext_vector_type(8))) short short8;
typedef __attribute__((ext_vector_type(4))) float f32x4;

#define HPAD 258
#define CIN 256
#define COUT 512
#define KTOT 2304  // 256*9
#define NT 36      // K-tiles of 64

// workspace partition (bytes)
#define WB_BYTES (COUT * KTOT * 2)
#define XBT_OFF  WB_BYTES
#define XBT_BYTES (HPAD * HPAD * CIN * 2)
#define ABSM_OFF (XBT_OFF + XBT_BYTES)
#define ABSM_BYTES (HPAD * HPAD * 4)
#define INK_OFF  (ABSM_OFF + ABSM_BYTES)

__device__ __forceinline__ UST f2bf(float f) {
  union { float f; u32 u; } c; c.f = f;
  u32 u = c.u;
  u += 0x7FFFu + ((u >> 16) & 1u);
  return (UST)(u >> 16);
}

__device__ __forceinline__ void gload_lds16(const void* g, void* l) {
  __builtin_amdgcn_global_load_lds(
      (const __attribute__((address_space(1))) u32*)g,
      (__attribute__((address_space(3))) u32*)l, 16, 0, 0);
}

// ---- kernel 1: alpha-fold + reorder weights to [co][khkw*256+ci] bf16 ----
__global__ __launch_bounds__(256) void k_prep_w(const float* __restrict__ w,
                                                UST* __restrict__ wb) {
  int co = blockIdx.x;
  int ci = threadIdx.x;
  const float* wr = w + co * KTOT + ci * 9;
  float v[9];
  float s = 0.f;
#pragma unroll
  for (int j = 0; j < 9; ++j) { v[j] = wr[j]; s += v[j]; }
  __shared__ float red[256];
  red[ci] = s;
  __syncthreads();
#pragma unroll
  for (int off = 128; off > 0; off >>= 1) {
    if (ci < off) red[ci] += red[ci + off];
    __syncthreads();
  }
  float alpha = red[0] * (1.0f / 2304.0f);
  UST* wo = wb + co * KTOT + ci;
#pragma unroll
  for (int j = 0; j < 9; ++j) wo[j * 256] = f2bf(v[j] * alpha);
}

// ---- kernel 2: binarize + NCHW->NHWC transpose + channel-mean |x| ----
__global__ __launch_bounds__(256) void k_binz(const float* __restrict__ x,
                                              UST* __restrict__ xbt,
                                              float* __restrict__ absm) {
  int hp = blockIdx.x;
  int wt = blockIdx.y;
  int wpl = threadIdx.x & 63;
  int chunk = threadIdx.x >> 6;
  int wp = wt * 64 + wpl;
  bool valid = wp < HPAD;
  int hx = hp - 1, wx = wp - 1;
  bool inb = valid && ((unsigned)hx < 256u) && ((unsigned)wx < 256u);
  float asum = 0.f;
  u32 pk[32];
#pragma unroll
  for (int c2 = 0; c2 < 32; ++c2) {
    int ci = chunk * 64 + c2 * 2;
    float v0 = 1.0f, v1 = 1.0f;
    if (inb) {
      v0 = x[(unsigned)ci * 65536u + (unsigned)(hx * 256 + wx)];
      v1 = x[(unsigned)(ci + 1) * 65536u + (unsigned)(hx * 256 + wx)];
    }
    asum += fabsf(v0) + fabsf(v1);
    u32 s0 = (v0 >= 0.f) ? 0x3F80u : 0xBF80u;
    u32 s1 = (v1 >= 0.f) ? 0x3F80u : 0xBF80u;
    pk[c2] = s0 | (s1 << 16);
  }
  if (valid) {
    uint4* dst = (uint4*)(xbt + ((unsigned)(hp * HPAD + wp) * 256u + chunk * 64));
#pragma unroll
    for (int g = 0; g < 8; ++g)
      dst[g] = make_uint4(pk[g * 4], pk[g * 4 + 1], pk[g * 4 + 2], pk[g * 4 + 3]);
  }
  __shared__ float red[4][64];
  red[chunk][wpl] = asum;
  __syncthreads();
  if (chunk == 0 && valid) {
    float tot = red[0][wpl] + red[1][wpl] + red[2][wpl] + red[3][wpl];
    absm[hp * HPAD + wp] = tot * (1.0f / 256.0f);
  }
}

// ---- kernel 3: 3x3 box filter / 9 ----
__global__ __launch_bounds__(256) void k_inputk(const float* __restrict__ absm,
                                                float* __restrict__ inK) {
  int h = blockIdx.x, w = threadIdx.x;
  float s = 0.f;
#pragma unroll
  for (int dh = 0; dh < 3; ++dh)
#pragma unroll
    for (int dw = 0; dw < 3; ++dw) s += absm[(h + dh) * HPAD + (w + dw)];
  inK[h * 256 + w] = s * (1.0f / 9.0f);
}

// ---- kernel 4: 256x256-tile implicit-GEMM conv, rotated 4-group pipeline ----
// LDS layout (128 KiB):
//   A planes: lds + b*32768 + P*16384      [b=buffer, P=K-half]
//   B planes: lds + 65536 + b*32768 + P*16384
// Each plane: 256 rows x 32 k bf16, superrow-XOR swizzled (verified: 0 conflicts).
// Rotated per-tile schedule (reads always 1-2 groups ahead of consuming MFMA;
// MFMA(g3) AFTER the barrier to cover the next tile's g0 read-drain):
//   R(g1) | STAGE(t+1) | MFMA(g0) | R(g2) | MFMA(g1) | R(g3) | MFMA(g2)
//   | lgkm0 vmcnt0 barrier | R(g0 of t+1) | MFMA(g3)
#define MM(a, b, c) __builtin_amdgcn_mfma_f32_16x16x32_bf16(a, b, c, 0, 0, 0)

#define A_LDS(B, P) (lds + (B) * 32768 + (P) * 16384)
#define B_LDS(B, P) (lds + 65536 + (B) * 32768 + (P) * 16384)
#define RD_A(B, P, M) (*(const short8*)(A_LDS(B, P) + swzA[M]))
#define RD_B(B, P, N) (*(const short8*)(B_LDS(B, P) + swzB[N]))

// stage one K-half plane; SRC = uniform base for this tile (A: wb_b+t*128,
// B: xbt_b + pixrow*512 + (t&3)*128); per-lane offsets aoff/boff pre-swizzled
#define STAGE_A(SRC, P, B) do { \
    const char* s_ = (SRC) + (P) * 64; \
    char* d_ = A_LDS(B, P) + wv * 1024; \
    gload_lds16(s_ + aoff0, d_); \
    gload_lds16(s_ + aoff1, d_ + 8192); } while (0)

#define STAGE_B(SRC, P, B) do { \
    const char* s_ = (SRC) + (P) * 64; \
    char* d_ = B_LDS(B, P) + wv * 1024; \
    gload_lds16(s_ + boff0, d_); \
    gload_lds16(s_ + boff1, d_ + 8192); } while (0)

#define MFMA_BEGIN \
  __builtin_amdgcn_sched_barrier(0); \
  __builtin_amdgcn_s_setprio(1);
#define MFMA_END \
  __builtin_amdgcn_s_setprio(0); \
  __builtin_amdgcn_sched_barrier(0);

#define Q_LO(AA, BB) \
  _Pragma("unroll") for (int m = 0; m < 4; ++m) \
  _Pragma("unroll") for (int n = 0; n < 4; ++n) \
    acc[m][n] = MM(AA[m], BB[n], acc[m][n]);
#define Q_HI(AA, BB) \
  _Pragma("unroll") for (int m = 0; m < 4; ++m) \
  _Pragma("unroll") for (int n = 0; n < 4; ++n) \
    acc[m + 4][n] = MM(AA[m + 4], BB[n], acc[m + 4][n]);

// full body with staging + trailing read of next tile's g0
#define BODY(CUR, ASRC, BSRC) do { \
  A0_[4] = RD_A(CUR, 0, 4); A0_[5] = RD_A(CUR, 0, 5); \
  A0_[6] = RD_A(CUR, 0, 6); A0_[7] = RD_A(CUR, 0, 7); \
  STAGE_A((ASRC), 0, (CUR) ^ 1); STAGE_A((ASRC), 1, (CUR) ^ 1); \
  STAGE_B((BSRC), 0, (CUR) ^ 1); STAGE_B((BSRC), 1, (CUR) ^ 1); \
  MFMA_BEGIN; Q_LO(A0_, B0_); MFMA_END; \
  B1_[0] = RD_B(CUR, 1, 0); B1_[1] = RD_B(CUR, 1, 1); \
  B1_[2] = RD_B(CUR, 1, 2); B1_[3] = RD_B(CUR, 1, 3); \
  A1_[0] = RD_A(CUR, 1, 0); A1_[1] = RD_A(CUR, 1, 1); \
  A1_[2] = RD_A(CUR, 1, 2); A1_[3] = RD_A(CUR, 1, 3); \
  MFMA_BEGIN; Q_HI(A0_, B0_); MFMA_END; \
  A1_[4] = RD_A(CUR, 1, 4); A1_[5] = RD_A(CUR, 1, 5); \
  A1_[6] = RD_A(CUR, 1, 6); A1_[7] = RD_A(CUR, 1, 7); \
  MFMA_BEGIN; Q_LO(A1_, B1_); MFMA_END; \
  asm volatile("s_waitcnt lgkmcnt(0)" ::: "memory"); \
  asm volatile("s_waitcnt vmcnt(0)" ::: "memory"); \
  __builtin_amdgcn_s_barrier(); \
  B0_[0] = RD_B((CUR) ^ 1, 0, 0); B0_[1] = RD_B((CUR) ^ 1, 0, 1); \
  B0_[2] = RD_B((CUR) ^ 1, 0, 2); B0_[3] = RD_B((CUR) ^ 1, 0, 3); \
  A0_[0] = RD_A((CUR) ^ 1, 0, 0); A0_[1] = RD_A((CUR) ^ 1, 0, 1); \
  A0_[2] = RD_A((CUR) ^ 1, 0, 2); A0_[3] = RD_A((CUR) ^ 1, 0, 3); \
  MFMA_BEGIN; Q_HI(A1_, B1_); MFMA_END; \
} while (0)

// final tile: no staging, no trailing read
#define BODY_LAST(CUR) do { \
  A0_[4] = RD_A(CUR, 0, 4); A0_[5] = RD_A(CUR, 0, 5); \
  A0_[6] = RD_A(CUR, 0, 6); A0_[7] = RD_A(CUR, 0, 7); \
  MFMA_BEGIN; Q_LO(A0_, B0_); MFMA_END; \
  B1_[0] = RD_B(CUR, 1, 0); B1_[1] = RD_B(CUR, 1, 1); \
  B1_[2] = RD_B(CUR, 1, 2); B1_[3] = RD_B(CUR, 1, 3); \
  A1_[0] = RD_A(CUR, 1, 0); A1_[1] = RD_A(CUR, 1, 1); \
  A1_[2] = RD_A(CUR, 1, 2); A1_[3] = RD_A(CUR, 1, 3); \
  MFMA_BEGIN; Q_HI(A0_, B0_); MFMA_END; \
  A1_[4] = RD_A(CUR, 1, 4); A1_[5] = RD_A(CUR, 1, 5); \
  A1_[6] = RD_A(CUR, 1, 6); A1_[7] = RD_A(CUR, 1, 7); \
  MFMA_BEGIN; Q_LO(A1_, B1_); MFMA_END; \
  MFMA_BEGIN; Q_HI(A1_, B1_); MFMA_END; \
} while (0)

__global__ __launch_bounds__(512, 2) void k_conv8(const UST* __restrict__ wb,
                                                  const UST* __restrict__ xbt,
                                                  const float* __restrict__ inK,
                                                  float* __restrict__ out) {
  __shared__ __align__(16) char lds[131072];
  int tid = threadIdx.x;
  int lane = tid & 63;
  int wv = tid >> 6;
  int wm = wv >> 2, wn = wv & 3;
  int bid = blockIdx.x;
  int bs = (bid & 7) * 64 + (bid >> 3);  // XCD-bijective swizzle (512 % 8 == 0)
  int mt = bs & 1;
  int h = bs >> 1;
  int co0 = mt << 8;

  // staging per-thread offsets (inverse-swizzled global source, linear LDS dest)
  int aoff0, aoff1, boff0, boff1;
  {
    u32 ql0 = (u32)tid * 16u, ql1 = (u32)(512 + tid) * 16u;
    u32 sr0 = ql0 >> 7, s0 = ((ql0 >> 4) & 7u) ^ (sr0 & 7u);
    u32 row0 = (sr0 << 1) | (s0 >> 2), q0 = s0 & 3u;
    u32 sr1 = ql1 >> 7, s1 = ((ql1 >> 4) & 7u) ^ (sr1 & 7u);
    u32 row1 = (sr1 << 1) | (s1 >> 2), q1 = s1 & 3u;
    aoff0 = (co0 + (int)row0) * 4608 + (int)q0 * 16;
    aoff1 = (co0 + (int)row1) * 4608 + (int)q1 * 16;
    boff0 = (int)row0 * 512 + (int)q0 * 16;
    boff1 = (int)row1 * 512 + (int)q1 * 16;
  }
  // ds_read swizzled offsets within a plane
  int swzA[8], swzB[4];
#pragma unroll
  for (int m = 0; m < 8; ++m) {
    u32 row = (u32)(wm * 128 + m * 16 + (lane & 15));
    u32 q = (u32)(lane >> 4);
    u32 sr = row >> 1, s = ((row & 1u) << 2) | q;
    swzA[m] = (int)(sr * 128u + (s ^ (sr & 7u)) * 16u);
  }
#pragma unroll
  for (int n = 0; n < 4; ++n) {
    u32 row = (u32)(wn * 64 + n * 16 + (lane & 15));
    u32 q = (u32)(lane >> 4);
    u32 sr = row >> 1, s = ((row & 1u) << 2) | q;
    swzB[n] = (int)(sr * 128u + (s ^ (sr & 7u)) * 16u);
  }

  const char* wb_b = (const char*)wb;
  const char* xbt_b = (const char*)xbt;

  f32x4 acc[8][4];
#pragma unroll
  for (int m = 0; m < 8; ++m)
#pragma unroll
    for (int n = 0; n < 4; ++n) acc[m][n] = (f32x4){0.f, 0.f, 0.f, 0.f};

  short8 A0_[8], B0_[4], A1_[8], B1_[4];

  // prologue: stage tile 0 into buf 0, then preload its g0
  {
    const char* a0src = wb_b;
    const char* b0src = xbt_b + (h * HPAD) * 512;  // kh=0, kw=0, t&3=0
    STAGE_A(a0src, 0, 0); STAGE_A(a0src, 1, 0);
    STAGE_B(b0src, 0, 0); STAGE_B(b0src, 1, 0);
  }
  asm volatile("s_waitcnt vmcnt(0)" ::: "memory");
  __builtin_amdgcn_s_barrier();
  B0_[0] = RD_B(0, 0, 0); B0_[1] = RD_B(0, 0, 1);
  B0_[2] = RD_B(0, 0, 2); B0_[3] = RD_B(0, 0, 3);
  A0_[0] = RD_A(0, 0, 0); A0_[1] = RD_A(0, 0, 1);
  A0_[2] = RD_A(0, 0, 2); A0_[3] = RD_A(0, 0, 3);

  // main: 8 khkw groups of 4 tiles (t = 0..31), kh/kw advanced scalar
  int kh = 0, kw = 0;
  const char* bcur = xbt_b + (h * HPAD) * 512;
  for (int it = 0; it < 8; ++it) {
    int nkw = kw + 1, nkh = kh;
    if (nkw == 3) { nkw = 0; ++nkh; }
    const char* bnext = xbt_b + ((h + nkh) * HPAD + nkw) * 512;
    const char* acur = wb_b + it * 512;
#pragma unroll
    for (int sub = 0; sub < 4; ++sub) {
      const char* astage = acur + (sub + 1) * 128;
      const char* bstage = (sub < 3) ? (bcur + (sub + 1) * 128) : bnext;
      if (sub & 1) { BODY(1, astage, bstage); }
      else         { BODY(0, astage, bstage); }
    }
    kh = nkh; kw = nkw; bcur = bnext;
  }
  // khkw = 8 (kh=2, kw=2): t = 32..35
  {
    const char* acur = wb_b + 8 * 512;
    BODY(0, acur + 128, bcur + 128);      // t=32, stages t=33
    BODY(1, acur + 256, bcur + 256);      // t=33, stages t=34
    BODY(0, acur + 384, bcur + 384);      // t=34, stages t=35
    BODY_LAST(1);                          // t=35
  }

  // epilogue: scale by input_K, write NCHW
  int col = lane & 15, rg = lane >> 4;
  int pixbase = h * 256;
#pragma unroll
  for (int n = 0; n < 4; ++n) {
    int w = wn * 64 + n * 16 + col;
    float kv = inK[pixbase + w];
#pragma unroll
    for (int m = 0; m < 8; ++m) {
      int co = co0 + wm * 128 + m * 16 + rg * 4;
      float* o = out + (u32)co * 65536u + (u32)(pixbase + w);
#pragma unroll
      for (int r = 0; r < 4; ++r) o[(u32)r * 65536u] = acc[m][n][r] * kv;
    }
  }
}

extern "C" void kernel_launch(void* const* d_in, const int* in_sizes, int n_in,
                              void* d_out, int out_size, void* d_ws, size_t ws_size,
                              hipStream_t stream) {
  const float* x = (const float*)d_in[0];
  const float* w = (const float*)d_in[1];
  float* out = (float*)d_out;
  char* ws = (char*)d_ws;
  UST* wb = (UST*)ws;
  UST* xbt = (UST*)(ws + XBT_OFF);
  float* absm = (float*)(ws + ABSM_OFF);
  float* inK = (float*)(ws + INK_OFF);

  k_prep_w<<<COUT, 256, 0, stream>>>(w, wb);
  k_binz<<<dim3(HPAD, 5), 256, 0, stream>>>(x, xbt, absm);
  k_inputk<<<256, 256, 0, stream>>>(absm, inK);
  k_conv8<<<512, 512, 0, stream>>>(wb, xbt, inK, out);
}